// Round 6
// baseline (170.586 us; speedup 1.0000x reference)
//
#include <hip/hip_runtime.h>
#include <hip/hip_fp16.h>
#include <math.h>

#define B_ 4
#define SQ 1024
#define SK 2048
#define HH 1024
#define NHEAD 16
#define HDIM 64

typedef _Float16 f16;
typedef __attribute__((ext_vector_type(8))) _Float16 f16x8;
typedef __attribute__((ext_vector_type(4))) _Float16 f16x4;
typedef __attribute__((ext_vector_type(4))) float f32x4;
typedef unsigned int u32;

#define GLOAD_LDS16(gp, lp) __builtin_amdgcn_global_load_lds( \
    (const __attribute__((address_space(1))) u32*)(gp),        \
    (__attribute__((address_space(3))) u32*)(lp), 16, 0, 0)
#define GLOAD_LDS4(gp, lp) __builtin_amdgcn_global_load_lds(  \
    (const __attribute__((address_space(1))) u32*)(gp),        \
    (__attribute__((address_space(3))) u32*)(lp), 4, 0, 0)

// ---------------------------------------------------------------------------
// prep: [0,1024) transpose 4 W f32->f16 ; [1024,1056) mask -> f32 bias row.
// ---------------------------------------------------------------------------
__global__ __launch_bounds__(256) void prep_k(
    const float* __restrict__ W0, const float* __restrict__ W1,
    const float* __restrict__ W2, const float* __restrict__ W3,
    const int* __restrict__ mask,
    f16* __restrict__ WT, float* __restrict__ pbias)
{
    __shared__ f16 t[64 * 80];
    const int bid = blockIdx.x, tid = threadIdx.x;
    if (bid < 1024) {
        int z = bid >> 8, idx = bid & 255;
        const float* W = z == 0 ? W0 : z == 1 ? W1 : z == 2 ? W2 : W3;
        f16* out = WT + (size_t)z * HH * HH;
        const int r0 = (idx >> 4) * 64, c0 = (idx & 15) * 64;
#pragma unroll
        for (int p = 0; p < 4; p++) {
            int s = p * 256 + tid;
            int row = s >> 4, u = s & 15;
            float4 a = *(const float4*)(W + (size_t)(r0 + row) * HH + c0 + u * 4);
            f16x4 vv;
            vv[0] = (f16)a.x; vv[1] = (f16)a.y; vv[2] = (f16)a.z; vv[3] = (f16)a.w;
            *(f16x4*)(t + row * 80 + u * 4) = vv;
        }
        __syncthreads();
#pragma unroll
        for (int p = 0; p < 2; p++) {
            int s = p * 256 + tid;
            int n = s >> 3, u = s & 7;
            f16x8 vv;
#pragma unroll
            for (int j = 0; j < 8; j++) vv[j] = t[(u * 8 + j) * 80 + n];
            *(f16x8*)(out + (size_t)(c0 + n) * HH + r0 + u * 8) = vv;
        }
    } else {
        int j = (bid - 1024) * 256 + tid;           // 0..8191 over [B][SK]
        pbias[j] = mask[j] ? 0.f : -1e30f;
    }
}

// ---------------------------------------------------------------------------
// GEMM body: C = A[M,1024] @ BT[1024,1024]^T + bias. Tile TM x 128, BK=32,
// 4 waves (2x2), double-buffered LDS (1 barrier/iter), XOR swizzle
// x(row)=(row>>1)&3 on both sides, XCD swizzle.
// CASTA: A is f32, cast to f16 during reg-staged LDS write.
// OUTMODE: 0 f32 row-major; 1 f16 row-major; 2 f16 V^T [B*NH][HD][SK].
// ---------------------------------------------------------------------------
template <int TM, int OUTMODE, int CASTA>
__device__ __forceinline__ void gemm_body(
    const void* Ain, const f16* __restrict__ BT,
    const float* __restrict__ bias, void* __restrict__ Cout,
    int bid, int nwg, f16* sA, f16* sB)
{
    const int tid = threadIdx.x, lane = tid & 63, w = tid >> 6;
    const int swz = (bid & 7) * (nwg >> 3) + (bid >> 3);
    const int m0 = (swz >> 3) * TM;
    const int n0 = (swz & 7) * 128;
    const int wr = w >> 1, wc = w & 1;
    const int ql = lane & 15, g = lane >> 4;
    const int N = 1024, K = 1024;
    const int MF = TM / 32;
    const int ABUF = TM * 32;
    f32x4 acc[TM / 32][4] = {};

    auto stage = [&](int buf, int k0) {
        if (CASTA) {
            const float* A32 = (const float*)Ain;
#pragma unroll
            for (int p = 0; p < TM / 64; p++) {
                int s = p * 256 + tid;
                int row = s >> 2, u = s & 3;
                const float* ap = A32 + (size_t)(m0 + row) * K + k0 + u * 8;
                float4 a0 = *(const float4*)ap;
                float4 a1 = *(const float4*)(ap + 4);
                f16x8 v;
                v[0] = (f16)a0.x; v[1] = (f16)a0.y; v[2] = (f16)a0.z; v[3] = (f16)a0.w;
                v[4] = (f16)a1.x; v[5] = (f16)a1.y; v[6] = (f16)a1.z; v[7] = (f16)a1.w;
                *(f16x8*)(sA + buf * ABUF + row * 32 + ((u ^ ((row >> 1) & 3)) * 8)) = v;
            }
        } else {
            const f16* A16 = (const f16*)Ain;
#pragma unroll
            for (int p = 0; p < TM / 64; p++) {
                int s = p * 256 + tid;
                int row = s >> 2, us = ((s & 3) ^ ((row >> 1) & 3)) * 8;
                GLOAD_LDS16(A16 + (size_t)(m0 + row) * K + k0 + us,
                            sA + buf * ABUF + (p * 256 + w * 64) * 8);
            }
        }
#pragma unroll
        for (int p = 0; p < 2; p++) {
            int s = p * 256 + tid;
            int row = s >> 2, us = ((s & 3) ^ ((row >> 1) & 3)) * 8;
            GLOAD_LDS16(BT + (size_t)(n0 + row) * K + k0 + us,
                        sB + buf * 4096 + (p * 256 + w * 64) * 8);
        }
    };

    stage(0, 0);
    int cur = 0;
    for (int k0 = 0; k0 < K; k0 += 32) {
        __syncthreads();                        // buf[cur] staged
        if (k0 + 32 < K) stage(cur ^ 1, k0 + 32);
        f16x8 af[MF], bf[4];
#pragma unroll
        for (int m = 0; m < MF; m++) {
            int row = wr * (TM / 2) + m * 16 + ql;
            af[m] = *(const f16x8*)(sA + cur * ABUF + row * 32 + ((g ^ ((row >> 1) & 3)) * 8));
        }
#pragma unroll
        for (int n = 0; n < 4; n++) {
            int row = wc * 64 + n * 16 + ql;
            bf[n] = *(const f16x8*)(sB + cur * 4096 + row * 32 + ((g ^ ((row >> 1) & 3)) * 8));
        }
#pragma unroll
        for (int m = 0; m < MF; m++)
#pragma unroll
            for (int n = 0; n < 4; n++)
                acc[m][n] = __builtin_amdgcn_mfma_f32_16x16x32_f16(af[m], bf[n], acc[m][n], 0, 0, 0);
        cur ^= 1;
    }

    float bv[4];
#pragma unroll
    for (int n = 0; n < 4; n++) bv[n] = bias[n0 + wc * 64 + n * 16 + ql];
#pragma unroll
    for (int m = 0; m < MF; m++) {
        int row0 = m0 + wr * (TM / 2) + m * 16 + g * 4;
#pragma unroll
        for (int n = 0; n < 4; n++) {
            int col = n0 + wc * 64 + n * 16 + ql;
            if (OUTMODE == 2) {
                int bb = row0 >> 11, kk = row0 & 2047;
                int hh = col >> 6, dd = col & 63;
                f16x4 vv;
#pragma unroll
                for (int e = 0; e < 4; e++) vv[e] = (f16)(acc[m][n][e] + bv[n]);
                *(f16x4*)((f16*)Cout + ((size_t)(bb * NHEAD + hh) * HDIM + dd) * SK + kk) = vv;
            } else if (OUTMODE == 1) {
#pragma unroll
                for (int e = 0; e < 4; e++)
                    ((f16*)Cout)[(size_t)(row0 + e) * N + col] = (f16)(acc[m][n][e] + bv[n]);
            } else {
#pragma unroll
                for (int e = 0; e < 4; e++)
                    ((float*)Cout)[(size_t)(row0 + e) * N + col] = acc[m][n][e] + bv[n];
            }
        }
    }
}

// Merged Q/K/V projections with fused f32->f16 A cast.
__global__ __launch_bounds__(256) void qkv_gemm_k(
    const float* __restrict__ q, const float* __restrict__ k,
    const float* __restrict__ v, const f16* __restrict__ wT,
    const float* __restrict__ bq, const float* __restrict__ bk,
    const float* __restrict__ bv,
    f16* __restrict__ qp, f16* __restrict__ kp, f16* __restrict__ vt)
{
    __shared__ f16 sA[2 * 4096];
    __shared__ f16 sB[2 * 4096];
    const int bid = blockIdx.x;
    const size_t M1 = 1024 * 1024;
    if (bid < 512)
        gemm_body<64, 1, 1>(q, wT, bq, qp, bid, 512, sA, sB);
    else if (bid < 1024)
        gemm_body<128, 1, 1>(k, wT + M1, bk, kp, bid - 512, 512, sA, sB);
    else
        gemm_body<128, 2, 1>(v, wT + 2 * M1, bv, vt, bid - 1024, 512, sA, sB);
}

__global__ __launch_bounds__(256) void o_gemm_k(
    const f16* __restrict__ ctx, const f16* __restrict__ wT,
    const float* __restrict__ bo, float* __restrict__ out)
{
    __shared__ f16 sA[2 * 4096];
    __shared__ f16 sB[2 * 4096];
    gemm_body<64, 0, 0>(ctx, wT, bo, out, blockIdx.x, 512, sA, sB);
}

// ---------------------------------------------------------------------------
// Flash attention, f16 MFMA. 8 waves x 16 q-rows = 128 q-rows per block,
// one (b,h). KVBLK=64, double-buffered (2x-unrolled, static buffers),
// conflict-free swizzled P-LDS, log2 softmax + defer-max, XCD swizzle.
// ---------------------------------------------------------------------------
#define SC2 0.18033688f   /* 0.125 * log2(e) */
#define THR2 11.5f

__global__ __launch_bounds__(512, 4) void attn_mfma_k(
    const f16* __restrict__ qp,     // [B][SQ][H]
    const f16* __restrict__ kp,     // [B][SK][H]
    const f16* __restrict__ vt,     // [B*NH][HD][SK]
    const float* __restrict__ pbias,// [B][SK] 0 / -1e30
    f16* __restrict__ ctx)          // [B][SQ][H]
{
    // 64 consecutive flats (8 (b,h) sets = 4MB K/V) per XCD
    const int flat = ((int)blockIdx.x & 7) * 64 + ((int)blockIdx.x >> 3);
    const int qt = flat & 7, h = (flat >> 3) & 15, b = flat >> 7;
    const int q0 = qt * 128;
    const int tid = threadIdx.x, lane = tid & 63, w = tid >> 6;
    const int ql = lane & 15, g = lane >> 4;

    __shared__ f16 ks[2 * 4096];      // [buf][key64][d64], 16B-unit swz u^(key&7)
    __shared__ f16 vs[2 * 4096];      // [buf][d64][key64], 16B-unit swz u^(d&7)
    __shared__ f16 plds[8][16 * 64];  // per-wave P, row=64 f16, unit swz u^(ql&7)
    __shared__ float sbias[2][64];

    const f16* kbase = kp + (size_t)b * SK * HH + h * HDIM;
    const f16* vbase = vt + ((size_t)(b * NHEAD + h)) * HDIM * SK;
    const float* bbase = pbias + b * SK;

    f16x8 qf[2];
    {
        const f16* qb = qp + ((size_t)(b * SQ + q0 + w * 16 + ql)) * HH + h * HDIM + g * 8;
        qf[0] = *(const f16x8*)qb;
        qf[1] = *(const f16x8*)(qb + 32);
    }

    auto stageKV = [&](int buf, int kt) {
        int r = tid >> 3, ulg = ((tid & 7) ^ (r & 7)) * 8;
        GLOAD_LDS16(kbase + (size_t)(kt + r) * HH + ulg, ks + buf * 4096 + w * 512);
        GLOAD_LDS16(vbase + (size_t)r * SK + kt + ulg,   vs + buf * 4096 + w * 512);
        if (w == 0) GLOAD_LDS4(bbase + kt + lane, &sbias[buf][0]);
    };

    f32x4 oacc[4] = {};
    float mrun = -1e30f, lrun = 0.f;
    f16* pw = &plds[w][0];

    auto tile = [&](const f16* kb, const f16* vb, const float* sb,
                    bool pf_en, int pbuf, int pkt) {
        __syncthreads();                       // buf staged; prior reads done
        if (pf_en) stageKV(pbuf, pkt);

        // S^T = K . Q^T : sacc[n][e] = S[q=ql][key = n*16 + g*4 + e]
        f32x4 sacc[4] = {};
        __builtin_amdgcn_s_setprio(1);
#pragma unroll
        for (int n = 0; n < 4; n++) {
            int key = n * 16 + ql;
#pragma unroll
            for (int df = 0; df < 2; df++) {
                int u = df * 4 + g;
                f16x8 kf = *(const f16x8*)(kb + key * 64 + ((u ^ (key & 7)) * 8));
                sacc[n] = __builtin_amdgcn_mfma_f32_16x16x32_f16(kf, qf[df], sacc[n], 0, 0, 0);
            }
        }
        __builtin_amdgcn_s_setprio(0);

        float sv[4][4];
        float mt = -1e30f;
#pragma unroll
        for (int n = 0; n < 4; n++) {
            float4 b4 = *(const float4*)&sb[n * 16 + g * 4];
            float barr[4] = {b4.x, b4.y, b4.z, b4.w};
#pragma unroll
            for (int e = 0; e < 4; e++) {
                float s = fmaf(sacc[n][e], SC2, barr[e]);
                sv[n][e] = s;
                mt = fmaxf(mt, s);
            }
        }
        mt = fmaxf(mt, __shfl_xor(mt, 16, 64));
        mt = fmaxf(mt, __shfl_xor(mt, 32, 64));

        if (__any(mt > mrun + THR2)) {         // deferred rescale
            float mnew = fmaxf(mrun, mt);
            float alpha = __builtin_amdgcn_exp2f(mrun - mnew);
            mrun = mnew;
            lrun *= alpha;
            float al[4];
#pragma unroll
            for (int e = 0; e < 4; e++) al[e] = __shfl(alpha, g * 4 + e, 64);
#pragma unroll
            for (int df = 0; df < 4; df++)
#pragma unroll
                for (int e = 0; e < 4; e++) oacc[df][e] *= al[e];
        }

        float tsum = 0.f;
#pragma unroll
        for (int n = 0; n < 4; n++) {
            float p0 = __builtin_amdgcn_exp2f(sv[n][0] - mrun);
            float p1 = __builtin_amdgcn_exp2f(sv[n][1] - mrun);
            float p2 = __builtin_amdgcn_exp2f(sv[n][2] - mrun);
            float p3 = __builtin_amdgcn_exp2f(sv[n][3] - mrun);
            tsum += (p0 + p1) + (p2 + p3);
            f16x4 pv4;
            pv4[0] = (f16)p0; pv4[1] = (f16)p1; pv4[2] = (f16)p2; pv4[3] = (f16)p3;
            // unit u8 = 2n + (g>>1), within-unit offset (g&1)*4
            *(f16x4*)(pw + ql * 64 + (((2 * n + (g >> 1)) ^ (ql & 7)) * 8) + (g & 1) * 4) = pv4;
        }
        tsum += __shfl_xor(tsum, 16, 64);
        tsum += __shfl_xor(tsum, 32, 64);
        lrun += tsum;

        // O += P . V
        __builtin_amdgcn_s_setprio(1);
#pragma unroll
        for (int t = 0; t < 2; t++) {
            f16x8 pf = *(const f16x8*)(pw + ql * 64 + (((t * 4 + g) ^ (ql & 7)) * 8));
#pragma unroll
            for (int df = 0; df < 4; df++) {
                int d = df * 16 + ql;
                int u = t * 4 + g;
                f16x8 vf = *(const f16x8*)(vb + d * 64 + ((u ^ (d & 7)) * 8));
                oacc[df] = __builtin_amdgcn_mfma_f32_16x16x32_f16(pf, vf, oacc[df], 0, 0, 0);
            }
        }
        __builtin_amdgcn_s_setprio(0);
    };

    stageKV(0, 0);
#pragma unroll 1
    for (int kt = 0; kt < SK; kt += 128) {
        tile(ks, vs, sbias[0], true, 1, kt + 64);
        tile(ks + 4096, vs + 4096, sbias[1], kt + 128 < SK, 0, kt + 128);
    }

    float linv[4];
#pragma unroll
    for (int e = 0; e < 4; e++) {
        float lv = __shfl(lrun, g * 4 + e, 64);
        linv[e] = 1.f / lv;
    }
    f16* ob = ctx + ((size_t)(b * SQ + q0 + w * 16)) * HH + h * HDIM;
#pragma unroll
    for (int df = 0; df < 4; df++)
#pragma unroll
        for (int e = 0; e < 4; e++)
            ob[(size_t)(g * 4 + e) * HH + df * 16 + ql] = (f16)(oacc[df][e] * linv[e]);
}

// ---------------------------------------------------------------------------
extern "C" void kernel_launch(void* const* d_in, const int* in_sizes, int n_in,
                              void* d_out, int out_size, void* d_ws, size_t ws_size,
                              hipStream_t stream) {
    const float* query = (const float*)d_in[0];
    const float* key   = (const float*)d_in[1];
    const float* value = (const float*)d_in[2];
    const int*   mask  = (const int*)d_in[3];
    const float* Wq = (const float*)d_in[4];
    const float* bq = (const float*)d_in[5];
    const float* Wk = (const float*)d_in[6];
    const float* bk = (const float*)d_in[7];
    const float* Wv = (const float*)d_in[8];
    const float* bv = (const float*)d_in[9];
    const float* Wo = (const float*)d_in[10];
    const float* bo = (const float*)d_in[11];
    float* out = (float*)d_out;

    const size_t M1 = 1024 * 1024;
    f16* wT    = (f16*)d_ws;              // 4M f16
    f16* qp    = wT + 4 * M1;             // 4M
    f16* kp    = qp + 4 * M1;             // 8M
    f16* vt    = kp + 8 * M1;             // 8M
    f16* ctx   = vt + 8 * M1;             // 4M
    float* pbias = (float*)(ctx + 4 * M1);// 8192 f32

    dim3 blk(256);

    prep_k<<<dim3(1056), blk, 0, stream>>>(Wq, Wk, Wv, Wo, mask, wT, pbias);

    qkv_gemm_k<<<dim3(1536), blk, 0, stream>>>(query, key, value, wT,
                                               bq, bk, bv, qp, kp, vt);

    attn_mfma_k<<<dim3(512), dim3(512), 0, stream>>>(qp, kp, vt, pbias, ctx);

    o_gemm_k<<<dim3(512), blk, 0, stream>>>(ctx, wT + 3 * M1, bo, out);
}

// Round 7
// 154.836 us; speedup vs baseline: 1.1017x; 1.1017x over previous
//
#include <hip/hip_runtime.h>
#include <hip/hip_fp16.h>
#include <math.h>

#define B_ 4
#define SQ 1024
#define SK 2048
#define HH 1024
#define NHEAD 16
#define HDIM 64

typedef _Float16 f16;
typedef __attribute__((ext_vector_type(8))) _Float16 f16x8;
typedef __attribute__((ext_vector_type(4))) _Float16 f16x4;
typedef __attribute__((ext_vector_type(4))) float f32x4;
typedef unsigned int u32;

#define GLOAD_LDS16(gp, lp) __builtin_amdgcn_global_load_lds( \
    (const __attribute__((address_space(1))) u32*)(gp),        \
    (__attribute__((address_space(3))) u32*)(lp), 16, 0, 0)
#define GLOAD_LDS4(gp, lp) __builtin_amdgcn_global_load_lds(  \
    (const __attribute__((address_space(1))) u32*)(gp),        \
    (__attribute__((address_space(3))) u32*)(lp), 4, 0, 0)

// ---------------------------------------------------------------------------
// prep: [0,1024) transpose 4 W f32->f16 ; [1024,1056) mask -> f32 bias row.
// ---------------------------------------------------------------------------
__global__ __launch_bounds__(256) void prep_k(
    const float* __restrict__ W0, const float* __restrict__ W1,
    const float* __restrict__ W2, const float* __restrict__ W3,
    const int* __restrict__ mask,
    f16* __restrict__ WT, float* __restrict__ pbias)
{
    __shared__ f16 t[64 * 80];
    const int bid = blockIdx.x, tid = threadIdx.x;
    if (bid < 1024) {
        int z = bid >> 8, idx = bid & 255;
        const float* W = z == 0 ? W0 : z == 1 ? W1 : z == 2 ? W2 : W3;
        f16* out = WT + (size_t)z * HH * HH;
        const int r0 = (idx >> 4) * 64, c0 = (idx & 15) * 64;
#pragma unroll
        for (int p = 0; p < 4; p++) {
            int s = p * 256 + tid;
            int row = s >> 4, u = s & 15;
            float4 a = *(const float4*)(W + (size_t)(r0 + row) * HH + c0 + u * 4);
            f16x4 vv;
            vv[0] = (f16)a.x; vv[1] = (f16)a.y; vv[2] = (f16)a.z; vv[3] = (f16)a.w;
            *(f16x4*)(t + row * 80 + u * 4) = vv;
        }
        __syncthreads();
#pragma unroll
        for (int p = 0; p < 2; p++) {
            int s = p * 256 + tid;
            int n = s >> 3, u = s & 7;
            f16x8 vv;
#pragma unroll
            for (int j = 0; j < 8; j++) vv[j] = t[(u * 8 + j) * 80 + n];
            *(f16x8*)(out + (size_t)(c0 + n) * HH + r0 + u * 8) = vv;
        }
    } else {
        int j = (bid - 1024) * 256 + tid;           // 0..8191 over [B][SK]
        pbias[j] = mask[j] ? 0.f : -1e30f;
    }
}

// ---------------------------------------------------------------------------
// GEMM body: C = A[M,1024] @ BT[1024,1024]^T + bias. Tile TM x 128, BK=32,
// 4 waves (2x2), double-buffered LDS, XOR swizzle x(row)=(row>>1)&3 on both
// sides, XCD swizzle.
// CASTA=1: A is f32; T14 async split — f32 loads issued one full compute
// phase before their ds_write (2x-unrolled, static reg sets/buffers).
// OUTMODE: 0 f32 row-major; 1 f16 row-major; 2 f16 V^T [B*NH][HD][SK].
// ---------------------------------------------------------------------------
template <int TM, int OUTMODE, int CASTA>
__device__ __forceinline__ void gemm_body(
    const void* Ain, const f16* __restrict__ BT,
    const float* __restrict__ bias, void* __restrict__ Cout,
    int bid, int nwg, f16* sA, f16* sB)
{
    const int tid = threadIdx.x, lane = tid & 63, w = tid >> 6;
    const int swz = (bid & 7) * (nwg >> 3) + (bid >> 3);
    const int m0 = (swz >> 3) * TM;
    const int n0 = (swz & 7) * 128;
    const int wr = w >> 1, wc = w & 1;
    const int ql = lane & 15, g = lane >> 4;
    const int N = 1024, K = 1024;
    const int MF = TM / 32;
    const int ABUF = TM * 32;
    const int NP = TM / 64;
    f32x4 acc[MF][4] = {};

    const float* A32 = (const float*)Ain;
    const f16*   A16 = (const f16*)Ain;

    auto stageB = [&](int buf, int k0) {
#pragma unroll
        for (int p = 0; p < 2; p++) {
            int s = p * 256 + tid;
            int row = s >> 2, us = ((s & 3) ^ ((row >> 1) & 3)) * 8;
            GLOAD_LDS16(BT + (size_t)(n0 + row) * K + k0 + us,
                        sB + buf * 4096 + (p * 256 + w * 64) * 8);
        }
    };
    auto loadA = [&](int k0, float4* r) {
#pragma unroll
        for (int p = 0; p < NP; p++) {
            int s = p * 256 + tid;
            int row = s >> 2, u = s & 3;
            const float* ap = A32 + (size_t)(m0 + row) * K + k0 + u * 8;
            r[2 * p]     = *(const float4*)ap;
            r[2 * p + 1] = *(const float4*)(ap + 4);
        }
    };
    auto writeA = [&](int buf, const float4* r) {
#pragma unroll
        for (int p = 0; p < NP; p++) {
            int s = p * 256 + tid;
            int row = s >> 2, u = s & 3;
            float4 a0 = r[2 * p], a1 = r[2 * p + 1];
            f16x8 v;
            v[0] = (f16)a0.x; v[1] = (f16)a0.y; v[2] = (f16)a0.z; v[3] = (f16)a0.w;
            v[4] = (f16)a1.x; v[5] = (f16)a1.y; v[6] = (f16)a1.z; v[7] = (f16)a1.w;
            *(f16x8*)(sA + buf * ABUF + row * 32 + ((u ^ ((row >> 1) & 3)) * 8)) = v;
        }
    };
    auto stageA16 = [&](int buf, int k0) {
#pragma unroll
        for (int p = 0; p < NP; p++) {
            int s = p * 256 + tid;
            int row = s >> 2, us = ((s & 3) ^ ((row >> 1) & 3)) * 8;
            GLOAD_LDS16(A16 + (size_t)(m0 + row) * K + k0 + us,
                        sA + buf * ABUF + (p * 256 + w * 64) * 8);
        }
    };
    auto compute = [&](int buf) {
        f16x8 af[MF], bf[4];
#pragma unroll
        for (int m = 0; m < MF; m++) {
            int row = wr * (TM / 2) + m * 16 + ql;
            af[m] = *(const f16x8*)(sA + buf * ABUF + row * 32 + ((g ^ ((row >> 1) & 3)) * 8));
        }
#pragma unroll
        for (int n = 0; n < 4; n++) {
            int row = wc * 64 + n * 16 + ql;
            bf[n] = *(const f16x8*)(sB + buf * 4096 + row * 32 + ((g ^ ((row >> 1) & 3)) * 8));
        }
#pragma unroll
        for (int m = 0; m < MF; m++)
#pragma unroll
            for (int n = 0; n < 4; n++)
                acc[m][n] = __builtin_amdgcn_mfma_f32_16x16x32_f16(af[m], bf[n], acc[m][n], 0, 0, 0);
    };

    if (CASTA) {
        float4 r0[2 * NP], r1[2 * NP];
        // prologue: tile0 -> buf0; tile1 -> r0 (in flight across first compute)
        loadA(0, r0);
        stageB(0, 0);
        writeA(0, r0);          // waits only on r0's loads
        loadA(32, r0);
#pragma unroll 1
        for (int k0 = 0; k0 < K; k0 += 64) {
            // even iter: compute buf0; stage tile(k0+32) -> buf1
            __syncthreads();
            stageB(1, k0 + 32);
            if (k0 + 64 < K) loadA(k0 + 64, r1);
            compute(0);
            writeA(1, r0);      // r0 = A(k0+32), arrived a phase ago
            // odd iter: compute buf1; stage tile(k0+64) -> buf0
            __syncthreads();
            if (k0 + 64 < K) {
                stageB(0, k0 + 64);
                if (k0 + 96 < K) loadA(k0 + 96, r0);
            }
            compute(1);
            if (k0 + 64 < K) writeA(0, r1);
        }
    } else {
        stageA16(0, 0);
        stageB(0, 0);
        int cur = 0;
#pragma unroll 1
        for (int k0 = 0; k0 < K; k0 += 32) {
            __syncthreads();
            if (k0 + 32 < K) { stageA16(cur ^ 1, k0 + 32); stageB(cur ^ 1, k0 + 32); }
            compute(cur);
            cur ^= 1;
        }
    }

    float bv[4];
#pragma unroll
    for (int n = 0; n < 4; n++) bv[n] = bias[n0 + wc * 64 + n * 16 + ql];
#pragma unroll
    for (int m = 0; m < MF; m++) {
        int row0 = m0 + wr * (TM / 2) + m * 16 + g * 4;
#pragma unroll
        for (int n = 0; n < 4; n++) {
            int col = n0 + wc * 64 + n * 16 + ql;
            if (OUTMODE == 2) {
                int bb = row0 >> 11, kk = row0 & 2047;
                int hh = col >> 6, dd = col & 63;
                f16x4 vv;
#pragma unroll
                for (int e = 0; e < 4; e++) vv[e] = (f16)(acc[m][n][e] + bv[n]);
                *(f16x4*)((f16*)Cout + ((size_t)(bb * NHEAD + hh) * HDIM + dd) * SK + kk) = vv;
            } else if (OUTMODE == 1) {
#pragma unroll
                for (int e = 0; e < 4; e++)
                    ((f16*)Cout)[(size_t)(row0 + e) * N + col] = (f16)(acc[m][n][e] + bv[n]);
            } else {
#pragma unroll
                for (int e = 0; e < 4; e++)
                    ((float*)Cout)[(size_t)(row0 + e) * N + col] = acc[m][n][e] + bv[n];
            }
        }
    }
}

// Merged Q/K/V projections with fused (T14-split) f32->f16 A cast.
__global__ __launch_bounds__(256, 3) void qkv_gemm_k(
    const float* __restrict__ q, const float* __restrict__ k,
    const float* __restrict__ v, const f16* __restrict__ wT,
    const float* __restrict__ bq, const float* __restrict__ bk,
    const float* __restrict__ bv,
    f16* __restrict__ qp, f16* __restrict__ kp, f16* __restrict__ vt)
{
    __shared__ f16 sA[2 * 4096];
    __shared__ f16 sB[2 * 4096];
    const int bid = blockIdx.x;
    const size_t M1 = 1024 * 1024;
    if (bid < 512)
        gemm_body<64, 1, 1>(q, wT, bq, qp, bid, 512, sA, sB);
    else if (bid < 1024)
        gemm_body<128, 1, 1>(k, wT + M1, bk, kp, bid - 512, 512, sA, sB);
    else
        gemm_body<128, 2, 1>(v, wT + 2 * M1, bv, vt, bid - 1024, 512, sA, sB);
}

__global__ __launch_bounds__(256) void o_gemm_k(
    const f16* __restrict__ ctx, const f16* __restrict__ wT,
    const float* __restrict__ bo, float* __restrict__ out)
{
    __shared__ f16 sA[2 * 4096];
    __shared__ f16 sB[2 * 4096];
    gemm_body<64, 0, 0>(ctx, wT, bo, out, blockIdx.x, 512, sA, sB);
}

// ---------------------------------------------------------------------------
// Flash attention, f16 MFMA. 8 waves x 16 q-rows = 128 q-rows per block,
// one (b,h). KVBLK=64, double-buffered (2x-unrolled, static buffers),
// conflict-free swizzled P-LDS, log2 softmax + defer-max, XCD swizzle.
// ---------------------------------------------------------------------------
#define SC2 0.18033688f   /* 0.125 * log2(e) */
#define THR2 11.5f

__global__ __launch_bounds__(512, 4) void attn_mfma_k(
    const f16* __restrict__ qp,     // [B][SQ][H]
    const f16* __restrict__ kp,     // [B][SK][H]
    const f16* __restrict__ vt,     // [B*NH][HD][SK]
    const float* __restrict__ pbias,// [B][SK] 0 / -1e30
    f16* __restrict__ ctx)          // [B][SQ][H]
{
    // 64 consecutive flats (8 (b,h) sets = 4MB K/V) per XCD
    const int flat = ((int)blockIdx.x & 7) * 64 + ((int)blockIdx.x >> 3);
    const int qt = flat & 7, h = (flat >> 3) & 15, b = flat >> 7;
    const int q0 = qt * 128;
    const int tid = threadIdx.x, lane = tid & 63, w = tid >> 6;
    const int ql = lane & 15, g = lane >> 4;

    __shared__ f16 ks[2 * 4096];      // [buf][key64][d64], 16B-unit swz u^(key&7)
    __shared__ f16 vs[2 * 4096];      // [buf][d64][key64], 16B-unit swz u^(d&7)
    __shared__ f16 plds[8][16 * 64];  // per-wave P, row=64 f16, unit swz u^(ql&7)
    __shared__ float sbias[2][64];

    const f16* kbase = kp + (size_t)b * SK * HH + h * HDIM;
    const f16* vbase = vt + ((size_t)(b * NHEAD + h)) * HDIM * SK;
    const float* bbase = pbias + b * SK;

    f16x8 qf[2];
    {
        const f16* qb = qp + ((size_t)(b * SQ + q0 + w * 16 + ql)) * HH + h * HDIM + g * 8;
        qf[0] = *(const f16x8*)qb;
        qf[1] = *(const f16x8*)(qb + 32);
    }

    auto stageKV = [&](int buf, int kt) {
        int r = tid >> 3, ulg = ((tid & 7) ^ (r & 7)) * 8;
        GLOAD_LDS16(kbase + (size_t)(kt + r) * HH + ulg, ks + buf * 4096 + w * 512);
        GLOAD_LDS16(vbase + (size_t)r * SK + kt + ulg,   vs + buf * 4096 + w * 512);
        if (w == 0) GLOAD_LDS4(bbase + kt + lane, &sbias[buf][0]);
    };

    f32x4 oacc[4] = {};
    float mrun = -1e30f, lrun = 0.f;
    f16* pw = &plds[w][0];

    auto tile = [&](const f16* kb, const f16* vb, const float* sb,
                    bool pf_en, int pbuf, int pkt) {
        __syncthreads();                       // buf staged; prior reads done
        if (pf_en) stageKV(pbuf, pkt);

        // S^T = K . Q^T : sacc[n][e] = S[q=ql][key = n*16 + g*4 + e]
        f32x4 sacc[4] = {};
        __builtin_amdgcn_s_setprio(1);
#pragma unroll
        for (int n = 0; n < 4; n++) {
            int key = n * 16 + ql;
#pragma unroll
            for (int df = 0; df < 2; df++) {
                int u = df * 4 + g;
                f16x8 kf = *(const f16x8*)(kb + key * 64 + ((u ^ (key & 7)) * 8));
                sacc[n] = __builtin_amdgcn_mfma_f32_16x16x32_f16(kf, qf[df], sacc[n], 0, 0, 0);
            }
        }
        __builtin_amdgcn_s_setprio(0);

        float sv[4][4];
        float mt = -1e30f;
#pragma unroll
        for (int n = 0; n < 4; n++) {
            float4 b4 = *(const float4*)&sb[n * 16 + g * 4];
            float barr[4] = {b4.x, b4.y, b4.z, b4.w};
#pragma unroll
            for (int e = 0; e < 4; e++) {
                float s = fmaf(sacc[n][e], SC2, barr[e]);
                sv[n][e] = s;
                mt = fmaxf(mt, s);
            }
        }
        mt = fmaxf(mt, __shfl_xor(mt, 16, 64));
        mt = fmaxf(mt, __shfl_xor(mt, 32, 64));

        if (__any(mt > mrun + THR2)) {         // deferred rescale
            float mnew = fmaxf(mrun, mt);
            float alpha = __builtin_amdgcn_exp2f(mrun - mnew);
            mrun = mnew;
            lrun *= alpha;
            float al[4];
#pragma unroll
            for (int e = 0; e < 4; e++) al[e] = __shfl(alpha, g * 4 + e, 64);
#pragma unroll
            for (int df = 0; df < 4; df++)
#pragma unroll
                for (int e = 0; e < 4; e++) oacc[df][e] *= al[e];
        }

        float tsum = 0.f;
#pragma unroll
        for (int n = 0; n < 4; n++) {
            float p0 = __builtin_amdgcn_exp2f(sv[n][0] - mrun);
            float p1 = __builtin_amdgcn_exp2f(sv[n][1] - mrun);
            float p2 = __builtin_amdgcn_exp2f(sv[n][2] - mrun);
            float p3 = __builtin_amdgcn_exp2f(sv[n][3] - mrun);
            tsum += (p0 + p1) + (p2 + p3);
            f16x4 pv4;
            pv4[0] = (f16)p0; pv4[1] = (f16)p1; pv4[2] = (f16)p2; pv4[3] = (f16)p3;
            // unit u8 = 2n + (g>>1), within-unit offset (g&1)*4
            *(f16x4*)(pw + ql * 64 + (((2 * n + (g >> 1)) ^ (ql & 7)) * 8) + (g & 1) * 4) = pv4;
        }
        tsum += __shfl_xor(tsum, 16, 64);
        tsum += __shfl_xor(tsum, 32, 64);
        lrun += tsum;

        // O += P . V
        __builtin_amdgcn_s_setprio(1);
#pragma unroll
        for (int t = 0; t < 2; t++) {
            f16x8 pf = *(const f16x8*)(pw + ql * 64 + (((t * 4 + g) ^ (ql & 7)) * 8));
#pragma unroll
            for (int df = 0; df < 4; df++) {
                int d = df * 16 + ql;
                int u = t * 4 + g;
                f16x8 vf = *(const f16x8*)(vb + d * 64 + ((u ^ (d & 7)) * 8));
                oacc[df] = __builtin_amdgcn_mfma_f32_16x16x32_f16(pf, vf, oacc[df], 0, 0, 0);
            }
        }
        __builtin_amdgcn_s_setprio(0);
    };

    stageKV(0, 0);
#pragma unroll 1
    for (int kt = 0; kt < SK; kt += 128) {
        tile(ks, vs, sbias[0], true, 1, kt + 64);
        tile(ks + 4096, vs + 4096, sbias[1], kt + 128 < SK, 0, kt + 128);
    }

    float linv[4];
#pragma unroll
    for (int e = 0; e < 4; e++) {
        float lv = __shfl(lrun, g * 4 + e, 64);
        linv[e] = 1.f / lv;
    }
    f16* ob = ctx + ((size_t)(b * SQ + q0 + w * 16)) * HH + h * HDIM;
#pragma unroll
    for (int df = 0; df < 4; df++)
#pragma unroll
        for (int e = 0; e < 4; e++)
            ob[(size_t)(g * 4 + e) * HH + df * 16 + ql] = (f16)(oacc[df][e] * linv[e]);
}

// ---------------------------------------------------------------------------
extern "C" void kernel_launch(void* const* d_in, const int* in_sizes, int n_in,
                              void* d_out, int out_size, void* d_ws, size_t ws_size,
                              hipStream_t stream) {
    const float* query = (const float*)d_in[0];
    const float* key   = (const float*)d_in[1];
    const float* value = (const float*)d_in[2];
    const int*   mask  = (const int*)d_in[3];
    const float* Wq = (const float*)d_in[4];
    const float* bq = (const float*)d_in[5];
    const float* Wk = (const float*)d_in[6];
    const float* bk = (const float*)d_in[7];
    const float* Wv = (const float*)d_in[8];
    const float* bv = (const float*)d_in[9];
    const float* Wo = (const float*)d_in[10];
    const float* bo = (const float*)d_in[11];
    float* out = (float*)d_out;

    const size_t M1 = 1024 * 1024;
    f16* wT    = (f16*)d_ws;              // 4M f16
    f16* qp    = wT + 4 * M1;             // 4M
    f16* kp    = qp + 4 * M1;             // 8M
    f16* vt    = kp + 8 * M1;             // 8M
    f16* ctx   = vt + 8 * M1;             // 4M
    float* pbias = (float*)(ctx + 4 * M1);// 8192 f32

    dim3 blk(256);

    prep_k<<<dim3(1056), blk, 0, stream>>>(Wq, Wk, Wv, Wo, mask, wT, pbias);

    qkv_gemm_k<<<dim3(1536), blk, 0, stream>>>(query, key, value, wT,
                                               bq, bk, bv, qp, kp, vt);

    attn_mfma_k<<<dim3(512), dim3(512), 0, stream>>>(qp, kp, vt, pbias, ctx);

    o_gemm_k<<<dim3(512), blk, 0, stream>>>(ctx, wT + 3 * M1, bo, out);
}